// Round 6
// baseline (292.390 us; speedup 1.0000x reference)
//
#include <hip/hip_runtime.h>
#include <hip/hip_bf16.h>
#include <stdint.h>

// Problem constants
#define D    2048
#define H    16
#define HD   128
#define KV   4096
#define RSQRT_HD 0.08838834764831845f

typedef __attribute__((ext_vector_type(4))) float floatx4;

// ---------------- ws layout (floats) ----------------
// [0,6144)      qs   : q,k,v matvec sums (atomic accum)
// [6144,8192)   values (atomic accum)
// [8192,10240)  aout   (atomic accum)
// [10240,12288) h1     (atomic accum)
// [12288,14336) h2     (atomic accum)
// [14336,16384) x1
// [16384,81920) att [H][KV]
// memset region: first 14336 floats

// Split-K matvec: dst[y*D + col] += sum_{r in chunk} pre(xin[r]) * W[r*D+col]
// grid (64, nmat), block 512. pre = relu(x+prebias) when prebias!=null.
__global__ void k_matvec(const float* __restrict__ Wa, const float* __restrict__ Wb,
                         const float* __restrict__ Wc, const float* __restrict__ xin,
                         const float* __restrict__ prebias,
                         float* __restrict__ dst) {
    const float* W = (blockIdx.y == 0) ? Wa : (blockIdx.y == 1 ? Wb : Wc);
    float* d = dst + (size_t)blockIdx.y * D;
    int c0 = threadIdx.x * 4;
    int r0 = blockIdx.x * 32;
    floatx4 acc = {0.f, 0.f, 0.f, 0.f};
    for (int rb = 0; rb < 2; ++rb) {
        const float* Wp = W + (size_t)(r0 + rb * 16) * D + c0;
        floatx4 w[16];
#pragma unroll
        for (int i = 0; i < 16; ++i)
            w[i] = *reinterpret_cast<const floatx4*>(Wp + (size_t)i * D);
#pragma unroll
        for (int i = 0; i < 16; ++i) {
            int r = r0 + rb * 16 + i;
            float t = xin[r];
            if (prebias) t = fmaxf(t + prebias[r], 0.f);
            acc += t * w[i];
        }
    }
    atomicAdd(&d[c0 + 0], acc[0]);
    atomicAdd(&d[c0 + 1], acc[1]);
    atomicAdd(&d[c0 + 2], acc[2]);
    atomicAdd(&d[c0 + 3], acc[3]);
}

// One wave per output row kk: roll V and K caches, mask + 16 head logits.
// All 16 loads staged into registers before any store (MLP).
__global__ void k_roll_logits(const float* __restrict__ cache1,
                              const float* __restrict__ cache2,
                              const float* __restrict__ qs,   // sums: q,k,v at 0,D,2D
                              const float* __restrict__ bq,
                              const float* __restrict__ bk,
                              const float* __restrict__ bv,
                              float* __restrict__ outv,
                              float* __restrict__ outk,
                              float* __restrict__ att) {
    int wave = threadIdx.x >> 6;
    int lane = threadIdx.x & 63;
    int kk = blockIdx.x * 4 + wave;              // 0..4095
    float pc[8];
    bool nz = false;
    float* vdst = outv + (size_t)kk * D;
    float* kdst = outk + (size_t)kk * D;

    if (kk < KV - 1) {
        const float* vsrc = cache1 + (size_t)(kk + 1) * D;
        const float* ksrc = cache2 + (size_t)(kk + 1) * D;
        floatx4 v[8], k[8];
#pragma unroll
        for (int c = 0; c < 8; ++c)
            v[c] = *reinterpret_cast<const floatx4*>(vsrc + c * 256 + lane * 4);
#pragma unroll
        for (int c = 0; c < 8; ++c)
            k[c] = *reinterpret_cast<const floatx4*>(ksrc + c * 256 + lane * 4);
#pragma unroll
        for (int c = 0; c < 8; ++c) {
            int e = c * 256 + lane * 4;
            *reinterpret_cast<floatx4*>(vdst + e) = v[c];
            *reinterpret_cast<floatx4*>(kdst + e) = k[c];
            nz = nz | (v[c][0] != 0.f) | (v[c][1] != 0.f) | (v[c][2] != 0.f) | (v[c][3] != 0.f);
            floatx4 q4 = *reinterpret_cast<const floatx4*>(qs + e);
            floatx4 b4 = *reinterpret_cast<const floatx4*>(bq + e);
            q4 += b4;
            pc[c] = q4[0]*k[c][0] + q4[1]*k[c][1] + q4[2]*k[c][2] + q4[3]*k[c][3];
        }
    } else {
#pragma unroll
        for (int c = 0; c < 8; ++c) {
            int e = c * 256 + lane * 4;
            floatx4 v4 = *reinterpret_cast<const floatx4*>(qs + 2 * D + e);
            floatx4 k4 = *reinterpret_cast<const floatx4*>(qs + D + e);
            v4 += *reinterpret_cast<const floatx4*>(bv + e);
            k4 += *reinterpret_cast<const floatx4*>(bk + e);
            *reinterpret_cast<floatx4*>(vdst + e) = v4;
            *reinterpret_cast<floatx4*>(kdst + e) = k4;
            nz = nz | (v4[0] != 0.f) | (v4[1] != 0.f) | (v4[2] != 0.f) | (v4[3] != 0.f);
            floatx4 q4 = *reinterpret_cast<const floatx4*>(qs + e);
            q4 += *reinterpret_cast<const floatx4*>(bq + e);
            pc[c] = q4[0]*k4[0] + q4[1]*k4[1] + q4[2]*k4[2] + q4[3]*k4[3];
        }
    }

    unsigned long long bal = __ballot(nz ? 1 : 0);
    bool anynz = (bal != 0ULL);

    // chunk c covers heads 2c (lanes 0..31) and 2c+1 (lanes 32..63)
#pragma unroll
    for (int c = 0; c < 8; ++c) {
        float v = pc[c];
        v += __shfl_xor(v, 1);
        v += __shfl_xor(v, 2);
        v += __shfl_xor(v, 4);
        v += __shfl_xor(v, 8);
        v += __shfl_xor(v, 16);
        pc[c] = v;
    }
    if ((lane & 31) == 0) {
        int hi = lane >> 5;
#pragma unroll
        for (int c = 0; c < 8; ++c) {
            int h = c * 2 + hi;
            att[(size_t)h * KV + kk] = anynz ? pc[c] * RSQRT_HD : -INFINITY;
        }
    }
}

__global__ void k_softmax(float* __restrict__ att) {
    __shared__ float sred[4];
    int h = blockIdx.x;
    float* a = att + (size_t)h * KV;
    int t = threadIdx.x;
    float v[16];
    float m = -INFINITY;
#pragma unroll
    for (int i = 0; i < 16; ++i) {
        v[i] = a[i * 256 + t];
        m = fmaxf(m, v[i]);
    }
    for (int s = 32; s >= 1; s >>= 1) m = fmaxf(m, __shfl_xor(m, s));
    if ((t & 63) == 0) sred[t >> 6] = m;
    __syncthreads();
    m = fmaxf(fmaxf(sred[0], sred[1]), fmaxf(sred[2], sred[3]));
    __syncthreads();
    float sum = 0.f;
#pragma unroll
    for (int i = 0; i < 16; ++i) {
        v[i] = __expf(v[i] - m);
        sum += v[i];
    }
    for (int s = 32; s >= 1; s >>= 1) sum += __shfl_xor(sum, s);
    if ((t & 63) == 0) sred[t >> 6] = sum;
    __syncthreads();
    sum = sred[0] + sred[1] + sred[2] + sred[3];
    float inv = 1.0f / sum;
#pragma unroll
    for (int i = 0; i < 16; ++i) a[i * 256 + t] = v[i] * inv;
}

// values[h*HD+d] += sum_{kk in chunk} att[h,kk] * v[kk,h,d]; grid (64,H), 64 thr
__global__ void k_av(const float* __restrict__ outv,
                     const float* __restrict__ att,
                     float* __restrict__ values) {
    int h = blockIdx.y;
    int c = blockIdx.x;
    int lane = threadIdx.x;                      // 0..63
    int dg = (lane & 31) * 4;
    int ks = lane >> 5;                          // 0..1
    floatx4 acc = {0.f, 0.f, 0.f, 0.f};
    int kk0 = c * 64;
#pragma unroll 8
    for (int i = 0; i < 32; ++i) {
        int kk = kk0 + i * 2 + ks;
        float a = att[(size_t)h * KV + kk];
        floatx4 v4 = *reinterpret_cast<const floatx4*>(outv + (size_t)kk * D + h * HD + dg);
        acc += a * v4;
    }
#pragma unroll
    for (int j = 0; j < 4; ++j) acc[j] += __shfl_xor(acc[j], 32);
    if (lane < 32) {
        float* p = values + h * HD + dg;
        atomicAdd(&p[0], acc[0]);
        atomicAdd(&p[1], acc[1]);
        atomicAdd(&p[2], acc[2]);
        atomicAdd(&p[3], acc[3]);
    }
}

// out = LN(a + b + bb)*scale + bias
__global__ void k_ln(const float* __restrict__ a, const float* __restrict__ b,
                     const float* __restrict__ bb,
                     const float* __restrict__ sc, const float* __restrict__ bi,
                     float* __restrict__ out) {
    __shared__ float sred[4];
    int t = threadIdx.x;
    float loc[8];
    float s = 0.f;
#pragma unroll
    for (int i = 0; i < 8; ++i) {
        int e = i * 256 + t;
        float v = a[e] + b[e] + bb[e];
        loc[i] = v;
        s += v;
    }
    for (int m = 32; m >= 1; m >>= 1) s += __shfl_xor(s, m);
    if ((t & 63) == 0) sred[t >> 6] = s;
    __syncthreads();
    float mean = (sred[0] + sred[1] + sred[2] + sred[3]) * (1.0f / D);
    __syncthreads();
    float vs = 0.f;
#pragma unroll
    for (int i = 0; i < 8; ++i) {
        float d = loc[i] - mean;
        vs += d * d;
    }
    for (int m = 32; m >= 1; m >>= 1) vs += __shfl_xor(vs, m);
    if ((t & 63) == 0) sred[t >> 6] = vs;
    __syncthreads();
    float var = (sred[0] + sred[1] + sred[2] + sred[3]) * (1.0f / D);
    float inv = 1.0f / sqrtf(var + 1e-6f);
#pragma unroll
    for (int i = 0; i < 8; ++i) {
        int e = i * 256 + t;
        out[e] = (loc[i] - mean) * inv * sc[e] + bi[e];
    }
}

extern "C" void kernel_launch(void* const* d_in, const int* in_sizes, int n_in,
                              void* d_out, int out_size, void* d_ws, size_t ws_size,
                              hipStream_t stream) {
    const float* x      = (const float*)d_in[0];
    const float* cache1 = (const float*)d_in[1];
    const float* cache2 = (const float*)d_in[2];
    const float* Wv     = (const float*)d_in[3];
    const float* bv     = (const float*)d_in[4];
    const float* Wq     = (const float*)d_in[5];
    const float* bq     = (const float*)d_in[6];
    const float* Wk     = (const float*)d_in[7];
    const float* bk     = (const float*)d_in[8];
    const float* Wo     = (const float*)d_in[9];
    const float* bo     = (const float*)d_in[10];
    const float* W1     = (const float*)d_in[11];
    const float* b1     = (const float*)d_in[12];
    const float* W2     = (const float*)d_in[13];
    const float* b2     = (const float*)d_in[14];
    const float* l1s    = (const float*)d_in[15];
    const float* l1b    = (const float*)d_in[16];
    const float* l2s    = (const float*)d_in[17];
    const float* l2b    = (const float*)d_in[18];

    float* out   = (float*)d_out;
    float* outx2 = out;
    float* outv  = out + D;
    float* outk  = out + D + (size_t)KV * D;

    float* w      = (float*)d_ws;
    float* qs     = w + 0;        // q,k,v sums (3*D)
    float* values = w + 6144;
    float* aout   = w + 8192;
    float* h1     = w + 10240;
    float* h2     = w + 12288;
    float* x1     = w + 14336;
    float* att    = w + 16384;

    // zero all atomic accumulators (first 14336 floats)
    hipMemsetAsync(w, 0, 14336 * sizeof(float), stream);

    k_matvec<<<dim3(64, 3), 512, 0, stream>>>(Wq, Wk, Wv, x, nullptr, qs);
    k_roll_logits<<<KV / 4, 256, 0, stream>>>(cache1, cache2, qs, bq, bk, bv, outv, outk, att);
    k_softmax<<<H, 256, 0, stream>>>(att);
    k_av<<<dim3(64, H), 64, 0, stream>>>(outv, att, values);
    k_matvec<<<dim3(64, 1), 512, 0, stream>>>(Wo, Wo, Wo, values, nullptr, aout);
    k_ln<<<1, 256, 0, stream>>>(x, aout, bo, l1s, l1b, x1);
    k_matvec<<<dim3(64, 1), 512, 0, stream>>>(W1, W1, W1, x1, nullptr, h1);
    k_matvec<<<dim3(64, 1), 512, 0, stream>>>(W2, W2, W2, h1, b1, h2);
    k_ln<<<1, 256, 0, stream>>>(x1, h2, b2, l2s, l2b, outx2);
}